// Round 14
// baseline (842.670 us; speedup 1.0000x reference)
//
#include <hip/hip_runtime.h>

#define HH   128
#define H2   256
#define H3   384
#define NPT  65535      // nodes per tree (2^16 - 1)
#define TPB  512        // solo/leaf block size

typedef __bf16    bf16x8 __attribute__((ext_vector_type(8)));
typedef float     f32x4  __attribute__((ext_vector_type(4)));
typedef _Float16  f16x4  __attribute__((ext_vector_type(4)));
typedef _Float16  half_t;

typedef __attribute__((address_space(1))) const unsigned int gref_u32;
typedef __attribute__((address_space(3))) unsigned int       lref_u32;

__device__ unsigned short Wb_g[640 * 256];   // bf16 [row=output col j][k]; j<384: W_iou, else W_f

__device__ __forceinline__ float fsig(float x)  { return 1.0f / (1.0f + __expf(-x)); }
__device__ __forceinline__ float ftanh(float x) { return 1.0f - 2.0f / (__expf(2.0f * x) + 1.0f); }
__device__ __forceinline__ unsigned short f2bf(float f) {   // RNE fp32->bf16
    unsigned u = __float_as_uint(f);
    u += 0x7fffu + ((u >> 16) & 1u);
    return (unsigned short)(u >> 16);
}
__device__ __forceinline__ int swz(int off) { return off ^ (((off >> 9) & 7) << 4); }

// ---------------- weight convert ----------------
__global__ __launch_bounds__(256) void conv_k(const float* __restrict__ W_iou,
                                              const float* __restrict__ W_f)
{
    int t    = blockIdx.x * 256 + threadIdx.x;
    int base = t * 4;
    int j = base >> 8, k = base & 255;
    const float* src = (j < H3) ? (W_iou + j * H2 + k)
                                : (W_f + (j - H3) * H2 + k);
    float4 v = *(const float4*)src;
    ushort4 p;
    p.x = f2bf(v.x); p.y = f2bf(v.y); p.z = f2bf(v.z); p.w = f2bf(v.w);
    *(ushort4*)(Wb_g + base) = p;
}

// ---------------- leaf frontier (R10 version, no swizzle) ----------------
__global__ __launch_bounds__(256) void leaf_k(
    const float* __restrict__ iou, const float* __restrict__ c_in,
    const float* __restrict__ b_iou,
    float* __restrict__ h_out, half_t* __restrict__ c_ws,
    unsigned short* __restrict__ h_bf)
{
    int g    = blockIdx.x * 256 + threadIdx.x;
    int node = g >> 5;                           // 131072 leaf nodes
    int e    = (g & 31) << 2;
    int tree = node >> 15;
    int loc  = 32767 + (node & 32767);
    int row  = tree * NPT + loc;

    const float* ip = iou + (size_t)row * H3;
    float4 vi = *(const float4*)(ip + e);
    float4 vo = *(const float4*)(ip + HH + e);
    float4 vu = *(const float4*)(ip + 2 * HH + e);
    float4 vc = *(const float4*)(c_in + row * HH + e);
    float4 bi = *(const float4*)(b_iou + e);
    float4 bo = *(const float4*)(b_iou + HH + e);
    float4 bu = *(const float4*)(b_iou + 2 * HH + e);

    float4 hn, cn;
#define DOL(X) { float iv = fsig(vi.X + bi.X); float ov = fsig(vo.X + bo.X); \
                 float uv = ftanh(vu.X + bu.X); float cv = iv * uv + vc.X;   \
                 cn.X = cv; hn.X = ov * ftanh(cv); }
    DOL(x) DOL(y) DOL(z) DOL(w)
#undef DOL
    *(float4*)(h_out + row * HH + e) = hn;
    f16x4 cf; cf.x = (half_t)cn.x; cf.y = (half_t)cn.y; cf.z = (half_t)cn.z; cf.w = (half_t)cn.w;
    *(f16x4*)(c_ws + row * HH + e) = cf;
    ushort4 hb;
    hb.x = f2bf(hn.x); hb.y = f2bf(hn.y); hb.z = f2bf(hn.z); hb.w = f2bf(hn.w);
    *(ushort4*)(h_bf + row * HH + e) = hb;
}

// ---------------- internal level: 256 threads, 16-node tile, 8 blocks/CU target ----------------
// 4 waves; wave w owns output cols [32w,32w+32) of each of the 5 gate blocks:
// acc[sub][gate] = 40 VGPR. Single 8 KB LDS tile, async gload_lds staging
// (pre-swizzled source, linear LDS dest), ONE barrier per kernel.
__global__ __launch_bounds__(256, 8) void level_k(
    int lvl,
    const float* __restrict__ b_iou, const float* __restrict__ b_f,
    float* __restrict__ h_g, half_t* __restrict__ c_ws,
    unsigned short* __restrict__ h_bf)
{
    __shared__ __align__(16) unsigned short A_lds[16 * H2];   // 8 KB

    const int tid = threadIdx.x;
    const int w  = tid >> 6;            // wave 0..3
    const int lr = tid & 15;
    const int lc = (tid & 63) >> 4;
    const int node0 = blockIdx.x * 16;
    const int loc0  = (1 << lvl) - 1;
    const int lmask = loc0;

    // ---- async stage: 16 nodes' children h (8 KB), 2 x gload_lds per thread ----
#pragma unroll
    for (int it = 0; it < 2; ++it) {
        int item = tid + 256 * it;          // 512 chunks of 16B
        int m = item >> 5, u = item & 31;
        int node = node0 + m;
        int tree = node >> lvl;
        int loc  = loc0 + (node & lmask);
        int pairE = (tree * NPT + 2 * loc + 1) * HH;   // left-child row start (elems)
        int sb    = (u * 16) ^ ((m & 7) << 4);
        __builtin_amdgcn_global_load_lds(
            (gref_u32*)((const char*)h_bf + (size_t)pairE * 2 + sb),
            (lref_u32*)((char*)A_lds + item * 16), 16, 0, 0);
    }
    __syncthreads();   // drains vmcnt; tile ready

    // ---- MFMA: one m-tile (16 nodes), 2 sub x 5 gates ----
    f32x4 acc[2][5] = {};
    const unsigned short* Wp0 = Wb_g + (w * 32 + lr) * H2 + lc * 8;
    const unsigned short* Wp1 = Wp0 + 16 * H2;
#pragma unroll
    for (int kk = 0; kk < 8; ++kk) {
        bf16x8 a0 = *(const bf16x8*)((const char*)A_lds + swz(lr * 512 + kk * 64 + lc * 16));
#pragma unroll
        for (int g = 0; g < 5; ++g) {
            bf16x8 b0 = *(const bf16x8*)(Wp0 + g * HH * H2 + kk * 32);
            bf16x8 b1 = *(const bf16x8*)(Wp1 + g * HH * H2 + kk * 32);
            acc[0][g] = __builtin_amdgcn_mfma_f32_16x16x32_bf16(a0, b0, acc[0][g], 0, 0, 0);
            acc[1][g] = __builtin_amdgcn_mfma_f32_16x16x32_bf16(a0, b1, acc[1][g], 0, 0, 0);
        }
    }

    // ---- epilogue: sub-major (acc[0] dies before acc[1] peak); c loaded here ----
#pragma unroll
    for (int sub = 0; sub < 2; ++sub) {
        const int ee = w * 32 + sub * 16 + lr;
        const float bi = b_iou[ee], bo = b_iou[HH + ee], bu = b_iou[2 * HH + ee];
        const float bl = b_f[ee],   br = b_f[HH + ee];
#pragma unroll
        for (int r = 0; r < 4; ++r) {
            int node = node0 + lc * 4 + r;
            int tree = node >> lvl;
            int loc  = loc0 + (node & lmask);
            int base = tree * NPT + loc;
            int o    = base * HH + ee;
            int lro  = (base + loc + 1) * HH + ee;   // left child row offset
            float cl = (float)c_ws[lro];
            float cr = (float)c_ws[lro + HH];
            float pi = acc[sub][0][r] + bi;
            float po = acc[sub][1][r] + bo;
            float pu = acc[sub][2][r] + bu;
            float pl = acc[sub][3][r] + bl;
            float pr = acc[sub][4][r] + br;
            float cv = fsig(pi) * ftanh(pu) + fsig(pl) * cl + fsig(pr) * cr;
            float hv = fsig(po) * ftanh(cv);
            h_g[o]  = hv;
            c_ws[o] = (half_t)cv;
            h_bf[o] = f2bf(hv);
        }
    }
}

// ---------------- solo tail l=5..0: one block per tree, weights in registers ----------------
__global__ __launch_bounds__(TPB, 2) void solo_k(
    const float* __restrict__ b_iou, const float* __restrict__ b_f,
    float* __restrict__ h_g, half_t* __restrict__ c_ws,
    const unsigned short* __restrict__ h_bf)
{
    __shared__ __align__(16) unsigned char hb[32768];

    const int tid = threadIdx.x;
    const int w = tid >> 6, lr = tid & 15, lc = (tid & 63) >> 4;
    const int ee = w * 16 + lr;
    const int tb = blockIdx.x * NPT;
    const float bi = b_iou[ee], bo = b_iou[HH + ee], bu = b_iou[2 * HH + ee];
    const float bl = b_f[ee],   br = b_f[HH + ee];

    bf16x8 Bf[5][8];
    const unsigned short* Wp = Wb_g + ee * H2 + lc * 8;
#pragma unroll
    for (int g = 0; g < 5; ++g)
#pragma unroll
        for (int kk = 0; kk < 8; ++kk)
            Bf[g][kk] = *(const bf16x8*)(Wp + g * HH * H2 + kk * 32);

#pragma unroll
    for (int it = 0; it < 2; ++it) {
        int p = tid + TPB * it;
        int cc = p >> 4, q = p & 15;
        uint4 v = *(const uint4*)(h_bf + (tb + 63 + cc) * HH + q * 8);
        *(uint4*)(hb + swz(p * 16)) = v;
    }

#pragma unroll 1
    for (int l = 5; l >= 0; --l) {
        const int nl     = 1 << l;
        const int loc0   = nl - 1;
        const int cloc0  = 2 * nl - 1;
        const int cbase  = (l & 1) ? 0 : 16384;
        const int obase  = cbase ^ 16384;
        const bool mt1   = (nl > 16);

        __syncthreads();

        f32x4 acc[2][5] = {};
#pragma unroll
        for (int kk = 0; kk < 8; ++kk) {
            bf16x8 a0 = *(const bf16x8*)(hb + cbase + swz(lr * 512 + kk * 64 + lc * 16));
#pragma unroll
            for (int g = 0; g < 5; ++g)
                acc[0][g] = __builtin_amdgcn_mfma_f32_16x16x32_bf16(a0, Bf[g][kk], acc[0][g], 0, 0, 0);
            if (mt1) {
                bf16x8 a1 = *(const bf16x8*)(hb + cbase + swz((16 + lr) * 512 + kk * 64 + lc * 16));
#pragma unroll
                for (int g = 0; g < 5; ++g)
                    acc[1][g] = __builtin_amdgcn_mfma_f32_16x16x32_bf16(a1, Bf[g][kk], acc[1][g], 0, 0, 0);
            }
        }
        __syncthreads();

#pragma unroll
        for (int mt = 0; mt < 2; ++mt)
#pragma unroll
            for (int r = 0; r < 4; ++r) {
                int j = mt * 16 + lc * 4 + r;
                if (j >= nl) continue;
                int row  = tb + loc0 + j;
                int lrow = tb + cloc0 + 2 * j;
                float cl = (float)c_ws[lrow * HH + ee];
                float cr = (float)c_ws[lrow * HH + HH + ee];
                float pi = acc[mt][0][r] + bi;
                float po = acc[mt][1][r] + bo;
                float pu = acc[mt][2][r] + bu;
                float pl = acc[mt][3][r] + bl;
                float pr = acc[mt][4][r] + br;
                float cv = fsig(pi) * ftanh(pu) + fsig(pl) * cl + fsig(pr) * cr;
                float hv = fsig(po) * ftanh(cv);
                h_g[row * HH + ee]  = hv;
                c_ws[row * HH + ee] = (half_t)cv;
                *(unsigned short*)(hb + obase + swz(j * 256 + ee * 2)) = f2bf(hv);
            }
    }
}

extern "C" void kernel_launch(void* const* d_in, const int* in_sizes, int n_in,
                              void* d_out, int out_size, void* d_ws, size_t ws_size,
                              hipStream_t stream)
{
    const float* iou   = (const float*)d_in[0];
    const float* c_in  = (const float*)d_in[2];
    const float* W_iou = (const float*)d_in[3];
    const float* b_iou = (const float*)d_in[4];
    const float* W_f   = (const float*)d_in[5];
    const float* b_f   = (const float*)d_in[6];
    float* h_out = (float*)d_out;
    half_t* c_ws = (half_t*)d_ws;                                                       // 67 MiB f16 c
    unsigned short* h_bf = (unsigned short*)((char*)d_ws + (size_t)72 * 1024 * 1024);   // 67 MiB bf16 h

    conv_k<<<160, 256, 0, stream>>>(W_iou, W_f);
    leaf_k<<<16384, 256, 0, stream>>>(iou, c_in, b_iou, h_out, c_ws, h_bf);

    for (int l = 14; l >= 6; --l) {
        int blocks = (4 << l) / 16;
        level_k<<<blocks, 256, 0, stream>>>(l, b_iou, b_f, h_out, c_ws, h_bf);
    }
    solo_k<<<4, TPB, 0, stream>>>(b_iou, b_f, h_out, c_ws, h_bf);
}

// Round 15
// 408.014 us; speedup vs baseline: 2.0653x; 2.0653x over previous
//
#include <hip/hip_runtime.h>

#define HH   128
#define H2   256
#define H3   384
#define NPT  65535      // nodes per tree (2^16 - 1)
#define TPB  512

typedef __bf16    bf16x8 __attribute__((ext_vector_type(8)));
typedef float     f32x4  __attribute__((ext_vector_type(4)));
typedef _Float16  f16x4  __attribute__((ext_vector_type(4)));
typedef _Float16  half_t;

__device__ unsigned short Wb_g[640 * 256];   // bf16 [row=output col j][k]; j<384: W_iou, else W_f

__device__ __forceinline__ float fsig(float x)  { return 1.0f / (1.0f + __expf(-x)); }
__device__ __forceinline__ float ftanh(float x) { return 1.0f - 2.0f / (__expf(2.0f * x) + 1.0f); }
__device__ __forceinline__ unsigned short f2bf(float f) {   // RNE fp32->bf16
    unsigned u = __float_as_uint(f);
    u += 0x7fffu + ((u >> 16) & 1u);
    return (unsigned short)(u >> 16);
}
__device__ __forceinline__ int swz(int off) { return off ^ (((off >> 9) & 7) << 4); }

// ---------------- weight convert ----------------
__global__ __launch_bounds__(256) void conv_k(const float* __restrict__ W_iou,
                                              const float* __restrict__ W_f)
{
    int t    = blockIdx.x * 256 + threadIdx.x;
    int base = t * 4;
    int j = base >> 8, k = base & 255;
    const float* src = (j < H3) ? (W_iou + j * H2 + k)
                                : (W_f + (j - H3) * H2 + k);
    float4 v = *(const float4*)src;
    ushort4 p;
    p.x = f2bf(v.x); p.y = f2bf(v.y); p.z = f2bf(v.z); p.w = f2bf(v.w);
    *(ushort4*)(Wb_g + base) = p;
}

// ---------------- leaf frontier ----------------
__global__ __launch_bounds__(256) void leaf_k(
    const float* __restrict__ iou, const float* __restrict__ c_in,
    const float* __restrict__ b_iou,
    float* __restrict__ h_out, half_t* __restrict__ c_ws,
    unsigned short* __restrict__ h_bf)
{
    int g    = blockIdx.x * 256 + threadIdx.x;
    int node = g >> 5;                           // 131072 leaf nodes
    int e    = (g & 31) << 2;
    int tree = node >> 15;
    int loc  = 32767 + (node & 32767);
    int row  = tree * NPT + loc;

    const float* ip = iou + (size_t)row * H3;
    float4 vi = *(const float4*)(ip + e);
    float4 vo = *(const float4*)(ip + HH + e);
    float4 vu = *(const float4*)(ip + 2 * HH + e);
    float4 vc = *(const float4*)(c_in + row * HH + e);
    float4 bi = *(const float4*)(b_iou + e);
    float4 bo = *(const float4*)(b_iou + HH + e);
    float4 bu = *(const float4*)(b_iou + 2 * HH + e);

    float4 hn, cn;
#define DOL(X) { float iv = fsig(vi.X + bi.X); float ov = fsig(vo.X + bo.X); \
                 float uv = ftanh(vu.X + bu.X); float cv = iv * uv + vc.X;   \
                 cn.X = cv; hn.X = ov * ftanh(cv); }
    DOL(x) DOL(y) DOL(z) DOL(w)
#undef DOL
    *(float4*)(h_out + row * HH + e) = hn;
    f16x4 cf; cf.x = (half_t)cn.x; cf.y = (half_t)cn.y; cf.z = (half_t)cn.z; cf.w = (half_t)cn.w;
    *(f16x4*)(c_ws + row * HH + e) = cf;
    ushort4 hb;
    hb.x = f2bf(hn.x); hb.y = f2bf(hn.y); hb.z = f2bf(hn.z); hb.w = f2bf(hn.w);
    *(ushort4*)(h_bf + row * HH + e) = hb;
}

// ---------------- internal level: barrier-free, LDS-free, per-wave pipeline ----------------
// 512 threads = 8 independent waves over a 32-node tile. Wave w owns output cols
// {g*128 + w*16 + lr}. Lane (lr,lc) loads A-fragments for rows lr and lr+16
// DIRECTLY from global h_bf: 16x dwordx4 with compile-time offsets, all in
// flight at once. 16 c-loads issued before the MFMA loop. No LDS, no barriers.
__global__ __launch_bounds__(TPB, 3) void level_k(
    int lvl,
    const float* __restrict__ b_iou, const float* __restrict__ b_f,
    float* __restrict__ h_g, half_t* __restrict__ c_ws,
    unsigned short* __restrict__ h_bf)
{
    const int tid = threadIdx.x;
    const int w  = tid >> 6;            // wave 0..7
    const int lr = tid & 15;
    const int lc = (tid & 63) >> 4;
    const int ee = w * 16 + lr;
    const int node0 = blockIdx.x * 32;
    const int loc0  = (1 << lvl) - 1;
    const int lmask = loc0;

    // ---- base addresses of the two A-rows (nodes) this lane reads ----
    int n0 = node0 + lr;
    int n1 = n0 + 16;
    int pr0 = ((n0 >> lvl) * NPT + 2 * (loc0 + (n0 & lmask)) + 1) * HH;
    int pr1 = ((n1 >> lvl) * NPT + 2 * (loc0 + (n1 & lmask)) + 1) * HH;
    const unsigned short* A0 = h_bf + pr0 + lc * 8;
    const unsigned short* A1 = h_bf + pr1 + lc * 8;

    // ---- all 16 A-fragment loads issued up front (static offsets) ----
    bf16x8 a0[8], a1[8];
#pragma unroll
    for (int kk = 0; kk < 8; ++kk) {
        const int off = (kk & 3) * 32 + (kk >> 2) * HH;   // right child at +HH
        a0[kk] = *(const bf16x8*)(A0 + off);
        a1[kk] = *(const bf16x8*)(A1 + off);
    }

    // ---- output offsets + 16 child-c loads, overlap with MFMA ----
    int   rofs[2][4];
    float clv[2][4], crv[2][4];
#pragma unroll
    for (int mt = 0; mt < 2; ++mt)
#pragma unroll
        for (int r = 0; r < 4; ++r) {
            int node = node0 + mt * 16 + lc * 4 + r;
            int tree = node >> lvl;
            int loc  = loc0 + (node & lmask);
            int base = tree * NPT + loc;
            int lro  = (base + loc + 1) * HH + ee;   // left child row offset
            rofs[mt][r] = base * HH + ee;
            clv[mt][r] = (float)c_ws[lro];
            crv[mt][r] = (float)c_ws[lro + HH];
        }

    // ---- MFMA: 80 per wave, b-fragments from L2-hot Wb_g ----
    f32x4 acc[2][5] = {};
    const unsigned short* Wp = Wb_g + ee * H2 + lc * 8;
#pragma unroll
    for (int kk = 0; kk < 8; ++kk)
#pragma unroll
        for (int g = 0; g < 5; ++g) {
            bf16x8 b = *(const bf16x8*)(Wp + g * HH * H2 + kk * 32);
            acc[0][g] = __builtin_amdgcn_mfma_f32_16x16x32_bf16(a0[kk], b, acc[0][g], 0, 0, 0);
            acc[1][g] = __builtin_amdgcn_mfma_f32_16x16x32_bf16(a1[kk], b, acc[1][g], 0, 0, 0);
        }

    // ---- epilogue ----
#pragma unroll
    for (int mt = 0; mt < 2; ++mt)
#pragma unroll
        for (int r = 0; r < 4; ++r) {
            const float bi = b_iou[ee], bo = b_iou[HH + ee], bu = b_iou[2 * HH + ee];
            const float bl = b_f[ee],   br = b_f[HH + ee];
            float pi = acc[mt][0][r] + bi;
            float po = acc[mt][1][r] + bo;
            float pu = acc[mt][2][r] + bu;
            float pl = acc[mt][3][r] + bl;
            float pr = acc[mt][4][r] + br;
            float cv = fsig(pi) * ftanh(pu) + fsig(pl) * clv[mt][r] + fsig(pr) * crv[mt][r];
            float hv = fsig(po) * ftanh(cv);
            int o = rofs[mt][r];
            h_g[o]  = hv;
            c_ws[o] = (half_t)cv;
            h_bf[o] = f2bf(hv);
        }
}

// ---------------- solo tail l=5..0: one block per tree, weights in registers ----------------
__global__ __launch_bounds__(TPB, 2) void solo_k(
    const float* __restrict__ b_iou, const float* __restrict__ b_f,
    float* __restrict__ h_g, half_t* __restrict__ c_ws,
    const unsigned short* __restrict__ h_bf)
{
    __shared__ __align__(16) unsigned char hb[32768];

    const int tid = threadIdx.x;
    const int w = tid >> 6, lr = tid & 15, lc = (tid & 63) >> 4;
    const int ee = w * 16 + lr;
    const int tb = blockIdx.x * NPT;
    const float bi = b_iou[ee], bo = b_iou[HH + ee], bu = b_iou[2 * HH + ee];
    const float bl = b_f[ee],   br = b_f[HH + ee];

    bf16x8 Bf[5][8];
    const unsigned short* Wp = Wb_g + ee * H2 + lc * 8;
#pragma unroll
    for (int g = 0; g < 5; ++g)
#pragma unroll
        for (int kk = 0; kk < 8; ++kk)
            Bf[g][kk] = *(const bf16x8*)(Wp + g * HH * H2 + kk * 32);

#pragma unroll
    for (int it = 0; it < 2; ++it) {
        int p = tid + TPB * it;
        int cc = p >> 4, q = p & 15;
        uint4 v = *(const uint4*)(h_bf + (tb + 63 + cc) * HH + q * 8);
        *(uint4*)(hb + swz(p * 16)) = v;
    }

#pragma unroll 1
    for (int l = 5; l >= 0; --l) {
        const int nl     = 1 << l;
        const int loc0   = nl - 1;
        const int cloc0  = 2 * nl - 1;
        const int cbase  = (l & 1) ? 0 : 16384;
        const int obase  = cbase ^ 16384;
        const bool mt1   = (nl > 16);

        __syncthreads();

        f32x4 acc[2][5] = {};
#pragma unroll
        for (int kk = 0; kk < 8; ++kk) {
            bf16x8 a0 = *(const bf16x8*)(hb + cbase + swz(lr * 512 + kk * 64 + lc * 16));
#pragma unroll
            for (int g = 0; g < 5; ++g)
                acc[0][g] = __builtin_amdgcn_mfma_f32_16x16x32_bf16(a0, Bf[g][kk], acc[0][g], 0, 0, 0);
            if (mt1) {
                bf16x8 a1 = *(const bf16x8*)(hb + cbase + swz((16 + lr) * 512 + kk * 64 + lc * 16));
#pragma unroll
                for (int g = 0; g < 5; ++g)
                    acc[1][g] = __builtin_amdgcn_mfma_f32_16x16x32_bf16(a1, Bf[g][kk], acc[1][g], 0, 0, 0);
            }
        }
        __syncthreads();

#pragma unroll
        for (int mt = 0; mt < 2; ++mt)
#pragma unroll
            for (int r = 0; r < 4; ++r) {
                int j = mt * 16 + lc * 4 + r;
                if (j >= nl) continue;
                int row  = tb + loc0 + j;
                int lrow = tb + cloc0 + 2 * j;
                float cl = (float)c_ws[lrow * HH + ee];
                float cr = (float)c_ws[lrow * HH + HH + ee];
                float pi = acc[mt][0][r] + bi;
                float po = acc[mt][1][r] + bo;
                float pu = acc[mt][2][r] + bu;
                float pl = acc[mt][3][r] + bl;
                float pr = acc[mt][4][r] + br;
                float cv = fsig(pi) * ftanh(pu) + fsig(pl) * cl + fsig(pr) * cr;
                float hv = fsig(po) * ftanh(cv);
                h_g[row * HH + ee]  = hv;
                c_ws[row * HH + ee] = (half_t)cv;
                *(unsigned short*)(hb + obase + swz(j * 256 + ee * 2)) = f2bf(hv);
            }
    }
}

extern "C" void kernel_launch(void* const* d_in, const int* in_sizes, int n_in,
                              void* d_out, int out_size, void* d_ws, size_t ws_size,
                              hipStream_t stream)
{
    const float* iou   = (const float*)d_in[0];
    const float* c_in  = (const float*)d_in[2];
    const float* W_iou = (const float*)d_in[3];
    const float* b_iou = (const float*)d_in[4];
    const float* W_f   = (const float*)d_in[5];
    const float* b_f   = (const float*)d_in[6];
    float* h_out = (float*)d_out;
    half_t* c_ws = (half_t*)d_ws;                                                       // 67 MiB f16 c
    unsigned short* h_bf = (unsigned short*)((char*)d_ws + (size_t)72 * 1024 * 1024);   // 67 MiB bf16 h

    conv_k<<<160, 256, 0, stream>>>(W_iou, W_f);
    leaf_k<<<16384, 256, 0, stream>>>(iou, c_in, b_iou, h_out, c_ws, h_bf);

    for (int l = 14; l >= 6; --l) {
        int blocks = (4 << l) / 32;
        level_k<<<blocks, TPB, 0, stream>>>(l, b_iou, b_f, h_out, c_ws, h_bf);
    }
    solo_k<<<4, TPB, 0, stream>>>(b_iou, b_f, h_out, c_ws, h_bf);
}

// Round 16
// 400.028 us; speedup vs baseline: 2.1065x; 1.0200x over previous
//
#include <hip/hip_runtime.h>

#define HH   128
#define H2   256
#define H3   384
#define NPT  65535      // nodes per tree (2^16 - 1)
#define TPB  512

typedef __bf16    bf16x8 __attribute__((ext_vector_type(8)));
typedef float     f32x4  __attribute__((ext_vector_type(4)));
typedef _Float16  f16x4  __attribute__((ext_vector_type(4)));
typedef _Float16  half_t;

__device__ unsigned short Wb_g[640 * 256];   // bf16 [row=output col j][k]; j<384: W_iou, else W_f

__device__ __forceinline__ float fsig(float x)  { return 1.0f / (1.0f + __expf(-x)); }
__device__ __forceinline__ float ftanh(float x) { return 1.0f - 2.0f / (__expf(2.0f * x) + 1.0f); }
__device__ __forceinline__ unsigned short f2bf(float f) {   // RNE fp32->bf16
    unsigned u = __float_as_uint(f);
    u += 0x7fffu + ((u >> 16) & 1u);
    return (unsigned short)(u >> 16);
}
__device__ __forceinline__ int swz(int off) { return off ^ (((off >> 9) & 7) << 4); }

// ---------------- weight convert ----------------
__global__ __launch_bounds__(256) void conv_k(const float* __restrict__ W_iou,
                                              const float* __restrict__ W_f)
{
    int t    = blockIdx.x * 256 + threadIdx.x;
    int base = t * 4;
    int j = base >> 8, k = base & 255;
    const float* src = (j < H3) ? (W_iou + j * H2 + k)
                                : (W_f + (j - H3) * H2 + k);
    float4 v = *(const float4*)src;
    ushort4 p;
    p.x = f2bf(v.x); p.y = f2bf(v.y); p.z = f2bf(v.z); p.w = f2bf(v.w);
    *(ushort4*)(Wb_g + base) = p;
}

// ---------------- leaf frontier ----------------
__global__ __launch_bounds__(256) void leaf_k(
    const float* __restrict__ iou, const float* __restrict__ c_in,
    const float* __restrict__ b_iou,
    float* __restrict__ h_out, half_t* __restrict__ c_ws,
    unsigned short* __restrict__ h_bf)
{
    int g    = blockIdx.x * 256 + threadIdx.x;
    int node = g >> 5;                           // 131072 leaf nodes
    int e    = (g & 31) << 2;
    int tree = node >> 15;
    int loc  = 32767 + (node & 32767);
    int row  = tree * NPT + loc;

    const float* ip = iou + (size_t)row * H3;
    float4 vi = *(const float4*)(ip + e);
    float4 vo = *(const float4*)(ip + HH + e);
    float4 vu = *(const float4*)(ip + 2 * HH + e);
    float4 vc = *(const float4*)(c_in + row * HH + e);
    float4 bi = *(const float4*)(b_iou + e);
    float4 bo = *(const float4*)(b_iou + HH + e);
    float4 bu = *(const float4*)(b_iou + 2 * HH + e);

    float4 hn, cn;
#define DOL(X) { float iv = fsig(vi.X + bi.X); float ov = fsig(vo.X + bo.X); \
                 float uv = ftanh(vu.X + bu.X); float cv = iv * uv + vc.X;   \
                 cn.X = cv; hn.X = ov * ftanh(cv); }
    DOL(x) DOL(y) DOL(z) DOL(w)
#undef DOL
    *(float4*)(h_out + row * HH + e) = hn;
    f16x4 cf; cf.x = (half_t)cn.x; cf.y = (half_t)cn.y; cf.z = (half_t)cn.z; cf.w = (half_t)cn.w;
    *(f16x4*)(c_ws + row * HH + e) = cf;
    ushort4 hb;
    hb.x = f2bf(hn.x); hb.y = f2bf(hn.y); hb.z = f2bf(hn.z); hb.w = f2bf(hn.w);
    *(ushort4*)(h_bf + row * HH + e) = hb;
}

// ---------------- internal level: weights fully register-resident ----------------
// 512 threads = 8 waves, 32-node tile. Wave w owns output cols {g*128 + w*16 + lr}.
// All 40 B-fragments (5 gates x 8 k-steps) preloaded into 160 VGPRs BEFORE the
// staging barrier (loads overlap staging); MFMA loop touches only LDS + regs.
__global__ __launch_bounds__(TPB, 2) void level_k(
    int lvl,
    const float* __restrict__ b_iou, const float* __restrict__ b_f,
    float* __restrict__ h_g, half_t* __restrict__ c_ws,
    unsigned short* __restrict__ h_bf)
{
    __shared__ __align__(16) unsigned short A_lds[32 * H2];   // 16 KB

    const int tid = threadIdx.x;
    const int w  = tid >> 6;            // wave 0..7
    const int lr = tid & 15;
    const int lc = (tid & 63) >> 4;
    const int ee = w * 16 + lr;
    const int node0 = blockIdx.x * 32;
    const int loc0  = (1 << lvl) - 1;
    const int lmask = loc0;

    // ---- 1. weight fragments -> registers (independent of staging, issued first) ----
    bf16x8 Bf[5][8];
    const unsigned short* Wp = Wb_g + ee * H2 + lc * 8;
#pragma unroll
    for (int g = 0; g < 5; ++g)
#pragma unroll
        for (int kk = 0; kk < 8; ++kk)
            Bf[g][kk] = *(const bf16x8*)(Wp + g * HH * H2 + kk * 32);

    // ---- 2. stage children h into swizzled LDS (coalesced uint4 route) ----
#pragma unroll
    for (int it = 0; it < 2; ++it) {
        int item = tid + TPB * it;
        int m = item >> 5, u = item & 31;
        int node = node0 + m;
        int tree = node >> lvl;
        int loc  = loc0 + (node & lmask);
        int coff = (tree * NPT + 2 * loc + 1 + (u >> 4)) * HH + (u & 15) * 8;
        uint4 v = *(const uint4*)(h_bf + coff);
        *(uint4*)((char*)A_lds + swz(m * 512 + u * 16)) = v;
    }
    __syncthreads();

    // ---- 3. MFMA: LDS + registers only ----
    f32x4 acc[2][5] = {};
#pragma unroll
    for (int kk = 0; kk < 8; ++kk) {
        bf16x8 a0 = *(const bf16x8*)((const char*)A_lds + swz(lr * 512 + kk * 64 + lc * 16));
        bf16x8 a1 = *(const bf16x8*)((const char*)A_lds + swz((16 + lr) * 512 + kk * 64 + lc * 16));
#pragma unroll
        for (int g = 0; g < 5; ++g) {
            acc[0][g] = __builtin_amdgcn_mfma_f32_16x16x32_bf16(a0, Bf[g][kk], acc[0][g], 0, 0, 0);
            acc[1][g] = __builtin_amdgcn_mfma_f32_16x16x32_bf16(a1, Bf[g][kk], acc[1][g], 0, 0, 0);
        }
    }

    // ---- 4. epilogue: c loads here (short chain), gates, stores ----
    const float bi = b_iou[ee], bo = b_iou[HH + ee], bu = b_iou[2 * HH + ee];
    const float bl = b_f[ee],   br = b_f[HH + ee];
#pragma unroll
    for (int mt = 0; mt < 2; ++mt)
#pragma unroll
        for (int r = 0; r < 4; ++r) {
            int node = node0 + mt * 16 + lc * 4 + r;
            int tree = node >> lvl;
            int loc  = loc0 + (node & lmask);
            int base = tree * NPT + loc;
            int o    = base * HH + ee;
            int lro  = (base + loc + 1) * HH + ee;   // left child row offset
            float cl = (float)c_ws[lro];
            float cr = (float)c_ws[lro + HH];
            float pi = acc[mt][0][r] + bi;
            float po = acc[mt][1][r] + bo;
            float pu = acc[mt][2][r] + bu;
            float pl = acc[mt][3][r] + bl;
            float pr = acc[mt][4][r] + br;
            float cv = fsig(pi) * ftanh(pu) + fsig(pl) * cl + fsig(pr) * cr;
            float hv = fsig(po) * ftanh(cv);
            h_g[o]  = hv;
            c_ws[o] = (half_t)cv;
            h_bf[o] = f2bf(hv);
        }
}

// ---------------- solo tail l=5..0: one block per tree, weights in registers ----------------
__global__ __launch_bounds__(TPB, 2) void solo_k(
    const float* __restrict__ b_iou, const float* __restrict__ b_f,
    float* __restrict__ h_g, half_t* __restrict__ c_ws,
    const unsigned short* __restrict__ h_bf)
{
    __shared__ __align__(16) unsigned char hb[32768];

    const int tid = threadIdx.x;
    const int w = tid >> 6, lr = tid & 15, lc = (tid & 63) >> 4;
    const int ee = w * 16 + lr;
    const int tb = blockIdx.x * NPT;
    const float bi = b_iou[ee], bo = b_iou[HH + ee], bu = b_iou[2 * HH + ee];
    const float bl = b_f[ee],   br = b_f[HH + ee];

    bf16x8 Bf[5][8];
    const unsigned short* Wp = Wb_g + ee * H2 + lc * 8;
#pragma unroll
    for (int g = 0; g < 5; ++g)
#pragma unroll
        for (int kk = 0; kk < 8; ++kk)
            Bf[g][kk] = *(const bf16x8*)(Wp + g * HH * H2 + kk * 32);

#pragma unroll
    for (int it = 0; it < 2; ++it) {
        int p = tid + TPB * it;
        int cc = p >> 4, q = p & 15;
        uint4 v = *(const uint4*)(h_bf + (tb + 63 + cc) * HH + q * 8);
        *(uint4*)(hb + swz(p * 16)) = v;
    }

#pragma unroll 1
    for (int l = 5; l >= 0; --l) {
        const int nl     = 1 << l;
        const int loc0   = nl - 1;
        const int cloc0  = 2 * nl - 1;
        const int cbase  = (l & 1) ? 0 : 16384;
        const int obase  = cbase ^ 16384;
        const bool mt1   = (nl > 16);

        __syncthreads();

        f32x4 acc[2][5] = {};
#pragma unroll
        for (int kk = 0; kk < 8; ++kk) {
            bf16x8 a0 = *(const bf16x8*)(hb + cbase + swz(lr * 512 + kk * 64 + lc * 16));
#pragma unroll
            for (int g = 0; g < 5; ++g)
                acc[0][g] = __builtin_amdgcn_mfma_f32_16x16x32_bf16(a0, Bf[g][kk], acc[0][g], 0, 0, 0);
            if (mt1) {
                bf16x8 a1 = *(const bf16x8*)(hb + cbase + swz((16 + lr) * 512 + kk * 64 + lc * 16));
#pragma unroll
                for (int g = 0; g < 5; ++g)
                    acc[1][g] = __builtin_amdgcn_mfma_f32_16x16x32_bf16(a1, Bf[g][kk], acc[1][g], 0, 0, 0);
            }
        }
        __syncthreads();

#pragma unroll
        for (int mt = 0; mt < 2; ++mt)
#pragma unroll
            for (int r = 0; r < 4; ++r) {
                int j = mt * 16 + lc * 4 + r;
                if (j >= nl) continue;
                int row  = tb + loc0 + j;
                int lrow = tb + cloc0 + 2 * j;
                float cl = (float)c_ws[lrow * HH + ee];
                float cr = (float)c_ws[lrow * HH + HH + ee];
                float pi = acc[mt][0][r] + bi;
                float po = acc[mt][1][r] + bo;
                float pu = acc[mt][2][r] + bu;
                float pl = acc[mt][3][r] + bl;
                float pr = acc[mt][4][r] + br;
                float cv = fsig(pi) * ftanh(pu) + fsig(pl) * cl + fsig(pr) * cr;
                float hv = fsig(po) * ftanh(cv);
                h_g[row * HH + ee]  = hv;
                c_ws[row * HH + ee] = (half_t)cv;
                *(unsigned short*)(hb + obase + swz(j * 256 + ee * 2)) = f2bf(hv);
            }
    }
}

extern "C" void kernel_launch(void* const* d_in, const int* in_sizes, int n_in,
                              void* d_out, int out_size, void* d_ws, size_t ws_size,
                              hipStream_t stream)
{
    const float* iou   = (const float*)d_in[0];
    const float* c_in  = (const float*)d_in[2];
    const float* W_iou = (const float*)d_in[3];
    const float* b_iou = (const float*)d_in[4];
    const float* W_f   = (const float*)d_in[5];
    const float* b_f   = (const float*)d_in[6];
    float* h_out = (float*)d_out;
    half_t* c_ws = (half_t*)d_ws;                                                       // 67 MiB f16 c
    unsigned short* h_bf = (unsigned short*)((char*)d_ws + (size_t)72 * 1024 * 1024);   // 67 MiB bf16 h

    conv_k<<<160, 256, 0, stream>>>(W_iou, W_f);
    leaf_k<<<16384, 256, 0, stream>>>(iou, c_in, b_iou, h_out, c_ws, h_bf);

    for (int l = 14; l >= 6; --l) {
        int blocks = (4 << l) / 32;
        level_k<<<blocks, TPB, 0, stream>>>(l, b_iou, b_f, h_out, c_ws, h_bf);
    }
    solo_k<<<4, TPB, 0, stream>>>(b_iou, b_f, h_out, c_ws, h_bf);
}

// Round 17
// 346.673 us; speedup vs baseline: 2.4307x; 1.1539x over previous
//
#include <hip/hip_runtime.h>

#define HH   128
#define H2   256
#define H3   384
#define NPT  65535      // nodes per tree (2^16 - 1)
#define TPB  512

typedef __bf16    bf16x8 __attribute__((ext_vector_type(8)));
typedef float     f32x4  __attribute__((ext_vector_type(4)));
typedef _Float16  f16x4  __attribute__((ext_vector_type(4)));
typedef _Float16  half_t;

__device__ unsigned short Wb_g[640 * 256];   // bf16 [row=output col j][k]; j<384: W_iou, else W_f

__device__ __forceinline__ float fsig(float x)  { return 1.0f / (1.0f + __expf(-x)); }
__device__ __forceinline__ float ftanh(float x) { return 1.0f - 2.0f / (__expf(2.0f * x) + 1.0f); }
__device__ __forceinline__ unsigned short f2bf(float f) {   // RNE fp32->bf16
    unsigned u = __float_as_uint(f);
    u += 0x7fffu + ((u >> 16) & 1u);
    return (unsigned short)(u >> 16);
}
__device__ __forceinline__ int swz(int off) { return off ^ (((off >> 9) & 7) << 4); }

// ---------------- weight convert ----------------
__global__ __launch_bounds__(256) void conv_k(const float* __restrict__ W_iou,
                                              const float* __restrict__ W_f)
{
    int t    = blockIdx.x * 256 + threadIdx.x;
    int base = t * 4;
    int j = base >> 8, k = base & 255;
    const float* src = (j < H3) ? (W_iou + j * H2 + k)
                                : (W_f + (j - H3) * H2 + k);
    float4 v = *(const float4*)src;
    ushort4 p;
    p.x = f2bf(v.x); p.y = f2bf(v.y); p.z = f2bf(v.z); p.w = f2bf(v.w);
    *(ushort4*)(Wb_g + base) = p;
}

#define GATES5(PI, PO, PU, PL, PR, CL, CR, HV, CV) \
    { CV = fsig(PI) * ftanh(PU) + fsig(PL) * (CL) + fsig(PR) * (CR); \
      HV = fsig(PO) * ftanh(CV); }

// ---------------- fused leaf + l=14 ----------------
// Block b owns l=14 nodes [32b, 32b+32) (all same tree) and their 64 leaf
// children = rows [lbase, lbase+64). Leaf phase computes gates elementwise,
// writes h fp32 to d_out, bf16 h straight into the swizzled LDS A-tile and
// f16 c into LDS. l=14 phase = R10 MFMA + epilogue with child-c from LDS.
// Leaf h_bf / c_ws global writes and l=14 staging reads are eliminated.
__global__ __launch_bounds__(TPB, 4) void leaf14_k(
    const float* __restrict__ iou, const float* __restrict__ c_in,
    const float* __restrict__ b_iou, const float* __restrict__ b_f,
    float* __restrict__ h_g, half_t* __restrict__ c_ws,
    unsigned short* __restrict__ h_bf)
{
    __shared__ __align__(16) unsigned short A_lds[32 * H2];   // 16 KB: h of 64 leaves, A-layout
    __shared__ __align__(16) half_t         C_lds[64 * HH];   // 16 KB: c of 64 leaves

    const int tid = threadIdx.x;
    const int w  = tid >> 6;
    const int lr = tid & 15;
    const int lc = (tid & 63) >> 4;
    const int ee = w * 16 + lr;
    const int node0 = blockIdx.x * 32;
    const int tree  = node0 >> 14;
    const int lbase = tree * NPT + 32767 + 2 * (node0 & 16383);   // first leaf row

    // ---- leaf phase: 2048 float4-items over [64 rows][32 float4] ----
#pragma unroll
    for (int it = 0; it < 4; ++it) {
        int p   = tid + TPB * it;
        int row = p >> 5;            // 0..63
        int e4  = p & 31;            // float4 index 0..31
        int grow = lbase + row;
        const float* ip = iou + (size_t)grow * H3 + e4 * 4;
        float4 vi = *(const float4*)(ip);
        float4 vo = *(const float4*)(ip + HH);
        float4 vu = *(const float4*)(ip + 2 * HH);
        float4 vc = *(const float4*)(c_in + (size_t)grow * HH + e4 * 4);
        float4 bi = *(const float4*)(b_iou + e4 * 4);
        float4 bo = *(const float4*)(b_iou + HH + e4 * 4);
        float4 bu = *(const float4*)(b_iou + 2 * HH + e4 * 4);

        float4 hn, cn;
#define DOL(X) { float iv = fsig(vi.X + bi.X); float ov = fsig(vo.X + bo.X); \
                 float uv = ftanh(vu.X + bu.X); float cv = iv * uv + vc.X;   \
                 cn.X = cv; hn.X = ov * ftanh(cv); }
        DOL(x) DOL(y) DOL(z) DOL(w)
#undef DOL
        *(float4*)(h_g + (size_t)grow * HH + e4 * 4) = hn;           // leaf output h
        f16x4 cf; cf.x = (half_t)cn.x; cf.y = (half_t)cn.y;
        cf.z = (half_t)cn.z; cf.w = (half_t)cn.w;
        *(f16x4*)(C_lds + row * HH + e4 * 4) = cf;                   // c -> LDS only
        int m = row >> 1, half = row & 1;                            // A[m][half*128 + e]
        uint2 pk;
        pk.x = (unsigned)f2bf(hn.x) | ((unsigned)f2bf(hn.y) << 16);
        pk.y = (unsigned)f2bf(hn.z) | ((unsigned)f2bf(hn.w) << 16);
        int byte = (m * 512 + half * 256 + e4 * 8) ^ ((m & 7) << 4); // swizzled (8B-safe)
        *(uint2*)((char*)A_lds + byte) = pk;
    }
    __syncthreads();

    // ---- l=14 phase: MFMA from LDS, c from LDS ----
    f32x4 acc[2][5] = {};
    const unsigned short* Wp = Wb_g + ee * H2 + lc * 8;
#pragma unroll
    for (int kk = 0; kk < 8; ++kk) {
        bf16x8 a0 = *(const bf16x8*)((const char*)A_lds + swz(lr * 512 + kk * 64 + lc * 16));
        bf16x8 a1 = *(const bf16x8*)((const char*)A_lds + swz((16 + lr) * 512 + kk * 64 + lc * 16));
#pragma unroll
        for (int g = 0; g < 5; ++g) {
            bf16x8 b = *(const bf16x8*)(Wp + g * HH * H2 + kk * 32);
            acc[0][g] = __builtin_amdgcn_mfma_f32_16x16x32_bf16(a0, b, acc[0][g], 0, 0, 0);
            acc[1][g] = __builtin_amdgcn_mfma_f32_16x16x32_bf16(a1, b, acc[1][g], 0, 0, 0);
        }
    }

    const float bi = b_iou[ee], bo = b_iou[HH + ee], bu = b_iou[2 * HH + ee];
    const float bl = b_f[ee],   br = b_f[HH + ee];
#pragma unroll
    for (int mt = 0; mt < 2; ++mt)
#pragma unroll
        for (int r = 0; r < 4; ++r) {
            int q    = mt * 16 + lc * 4 + r;           // node within tile
            int node = node0 + q;
            int base = tree * NPT + 16383 + (node & 16383);
            int o    = base * HH + ee;
            float cl = (float)C_lds[(2 * q) * HH + ee];
            float cr = (float)C_lds[(2 * q + 1) * HH + ee];
            float hv, cv;
            GATES5(acc[mt][0][r] + bi, acc[mt][1][r] + bo, acc[mt][2][r] + bu,
                   acc[mt][3][r] + bl, acc[mt][4][r] + br, cl, cr, hv, cv);
            h_g[o]  = hv;
            c_ws[o] = (half_t)cv;
            h_bf[o] = f2bf(hv);
        }
}

// ---------------- internal level (R10 exact): 32-node tile, VGPR-route staging ----------------
__global__ __launch_bounds__(TPB, 4) void level_k(
    int lvl,
    const float* __restrict__ b_iou, const float* __restrict__ b_f,
    float* __restrict__ h_g, half_t* __restrict__ c_ws,
    unsigned short* __restrict__ h_bf)
{
    __shared__ __align__(16) unsigned short A_lds[32 * H2];

    const int tid = threadIdx.x;
    const int w  = tid >> 6;
    const int lr = tid & 15;
    const int lc = (tid & 63) >> 4;
    const int ee = w * 16 + lr;
    const int node0 = blockIdx.x * 32;
    const int loc0  = (1 << lvl) - 1;
    const int lmask = loc0;

#pragma unroll
    for (int it = 0; it < 2; ++it) {
        int item = tid + TPB * it;
        int m = item >> 5, u = item & 31;
        int node = node0 + m;
        int tree = node >> lvl;
        int loc  = loc0 + (node & lmask);
        int coff = (tree * NPT + 2 * loc + 1 + (u >> 4)) * HH + (u & 15) * 8;
        uint4 v = *(const uint4*)(h_bf + coff);
        *(uint4*)((char*)A_lds + swz(m * 512 + u * 16)) = v;
    }
    __syncthreads();

    int   rofs[2][4];
    float clv[2][4], crv[2][4];
#pragma unroll
    for (int mt = 0; mt < 2; ++mt)
#pragma unroll
        for (int r = 0; r < 4; ++r) {
            int node = node0 + mt * 16 + lc * 4 + r;
            int tree = node >> lvl;
            int loc  = loc0 + (node & lmask);
            int base = tree * NPT + loc;
            int lrow = base + loc + 1;
            rofs[mt][r] = base * HH + ee;
            clv[mt][r] = (float)c_ws[lrow * HH + ee];
            crv[mt][r] = (float)c_ws[lrow * HH + HH + ee];
        }

    f32x4 acc[2][5] = {};
    const unsigned short* Wp = Wb_g + ee * H2 + lc * 8;
#pragma unroll
    for (int kk = 0; kk < 8; ++kk) {
        bf16x8 a0 = *(const bf16x8*)((const char*)A_lds + swz(lr * 512 + kk * 64 + lc * 16));
        bf16x8 a1 = *(const bf16x8*)((const char*)A_lds + swz((16 + lr) * 512 + kk * 64 + lc * 16));
#pragma unroll
        for (int g = 0; g < 5; ++g) {
            bf16x8 b = *(const bf16x8*)(Wp + g * HH * H2 + kk * 32);
            acc[0][g] = __builtin_amdgcn_mfma_f32_16x16x32_bf16(a0, b, acc[0][g], 0, 0, 0);
            acc[1][g] = __builtin_amdgcn_mfma_f32_16x16x32_bf16(a1, b, acc[1][g], 0, 0, 0);
        }
    }

    const float bi = b_iou[ee], bo = b_iou[HH + ee], bu = b_iou[2 * HH + ee];
    const float bl = b_f[ee],   br = b_f[HH + ee];
#pragma unroll
    for (int mt = 0; mt < 2; ++mt)
#pragma unroll
        for (int r = 0; r < 4; ++r) {
            float hv, cv;
            GATES5(acc[mt][0][r] + bi, acc[mt][1][r] + bo, acc[mt][2][r] + bu,
                   acc[mt][3][r] + bl, acc[mt][4][r] + br, clv[mt][r], crv[mt][r], hv, cv);
            int o = rofs[mt][r];
            h_g[o]  = hv;
            c_ws[o] = (half_t)cv;
            h_bf[o] = f2bf(hv);
        }
}

// ---------------- solo tail l=5..0: one block per tree, weights in registers ----------------
__global__ __launch_bounds__(TPB, 2) void solo_k(
    const float* __restrict__ b_iou, const float* __restrict__ b_f,
    float* __restrict__ h_g, half_t* __restrict__ c_ws,
    const unsigned short* __restrict__ h_bf)
{
    __shared__ __align__(16) unsigned char hb[32768];

    const int tid = threadIdx.x;
    const int w = tid >> 6, lr = tid & 15, lc = (tid & 63) >> 4;
    const int ee = w * 16 + lr;
    const int tb = blockIdx.x * NPT;
    const float bi = b_iou[ee], bo = b_iou[HH + ee], bu = b_iou[2 * HH + ee];
    const float bl = b_f[ee],   br = b_f[HH + ee];

    bf16x8 Bf[5][8];
    const unsigned short* Wp = Wb_g + ee * H2 + lc * 8;
#pragma unroll
    for (int g = 0; g < 5; ++g)
#pragma unroll
        for (int kk = 0; kk < 8; ++kk)
            Bf[g][kk] = *(const bf16x8*)(Wp + g * HH * H2 + kk * 32);

#pragma unroll
    for (int it = 0; it < 2; ++it) {
        int p = tid + TPB * it;
        int cc = p >> 4, q = p & 15;
        uint4 v = *(const uint4*)(h_bf + (tb + 63 + cc) * HH + q * 8);
        *(uint4*)(hb + swz(p * 16)) = v;
    }

#pragma unroll 1
    for (int l = 5; l >= 0; --l) {
        const int nl     = 1 << l;
        const int loc0   = nl - 1;
        const int cloc0  = 2 * nl - 1;
        const int cbase  = (l & 1) ? 0 : 16384;
        const int obase  = cbase ^ 16384;
        const bool mt1   = (nl > 16);

        __syncthreads();

        f32x4 acc[2][5] = {};
#pragma unroll
        for (int kk = 0; kk < 8; ++kk) {
            bf16x8 a0 = *(const bf16x8*)(hb + cbase + swz(lr * 512 + kk * 64 + lc * 16));
#pragma unroll
            for (int g = 0; g < 5; ++g)
                acc[0][g] = __builtin_amdgcn_mfma_f32_16x16x32_bf16(a0, Bf[g][kk], acc[0][g], 0, 0, 0);
            if (mt1) {
                bf16x8 a1 = *(const bf16x8*)(hb + cbase + swz((16 + lr) * 512 + kk * 64 + lc * 16));
#pragma unroll
                for (int g = 0; g < 5; ++g)
                    acc[1][g] = __builtin_amdgcn_mfma_f32_16x16x32_bf16(a1, Bf[g][kk], acc[1][g], 0, 0, 0);
            }
        }
        __syncthreads();

#pragma unroll
        for (int mt = 0; mt < 2; ++mt)
#pragma unroll
            for (int r = 0; r < 4; ++r) {
                int j = mt * 16 + lc * 4 + r;
                if (j >= nl) continue;
                int row  = tb + loc0 + j;
                int lrow = tb + cloc0 + 2 * j;
                float cl = (float)c_ws[lrow * HH + ee];
                float cr = (float)c_ws[lrow * HH + HH + ee];
                float hv, cv;
                GATES5(acc[mt][0][r] + bi, acc[mt][1][r] + bo, acc[mt][2][r] + bu,
                       acc[mt][3][r] + bl, acc[mt][4][r] + br, cl, cr, hv, cv);
                h_g[row * HH + ee]  = hv;
                c_ws[row * HH + ee] = (half_t)cv;
                *(unsigned short*)(hb + obase + swz(j * 256 + ee * 2)) = f2bf(hv);
            }
    }
}

extern "C" void kernel_launch(void* const* d_in, const int* in_sizes, int n_in,
                              void* d_out, int out_size, void* d_ws, size_t ws_size,
                              hipStream_t stream)
{
    const float* iou   = (const float*)d_in[0];
    const float* c_in  = (const float*)d_in[2];
    const float* W_iou = (const float*)d_in[3];
    const float* b_iou = (const float*)d_in[4];
    const float* W_f   = (const float*)d_in[5];
    const float* b_f   = (const float*)d_in[6];
    float* h_out = (float*)d_out;
    half_t* c_ws = (half_t*)d_ws;                                                       // 67 MiB f16 c
    unsigned short* h_bf = (unsigned short*)((char*)d_ws + (size_t)72 * 1024 * 1024);   // 67 MiB bf16 h

    conv_k<<<160, 256, 0, stream>>>(W_iou, W_f);
    leaf14_k<<<2048, TPB, 0, stream>>>(iou, c_in, b_iou, b_f, h_out, c_ws, h_bf);   // leaves + l=14
    for (int l = 13; l >= 6; --l) {
        int blocks = (4 << l) / 32;
        level_k<<<blocks, TPB, 0, stream>>>(l, b_iou, b_f, h_out, c_ws, h_bf);
    }
    solo_k<<<4, TPB, 0, stream>>>(b_iou, b_f, h_out, c_ws, h_bf);
}